// Round 6
// baseline (619.050 us; speedup 1.0000x reference)
//
#include <hip/hip_runtime.h>
#include <math.h>

#define T_LEN   16384
#define NB      2
#define FCH     80
#define NLAYERS 24
#define TFRAMES 68

typedef __attribute__((ext_vector_type(8))) short bf16x8;
typedef __attribute__((ext_vector_type(4))) float f32x4;

static __device__ inline unsigned short f2bf(float f) {
    unsigned int u = __float_as_uint(f);
    unsigned int r = (u + 0x7FFFu + ((u >> 16) & 1u)) >> 16;
    return (unsigned short)r;
}

// ---------------------------------------------------------------------------
// Pack: bf16 weight layouts + firstWT (transposed embedding table, bias folded)
// ---------------------------------------------------------------------------
__global__ void k_pack(const float* __restrict__ convW, const float* __restrict__ condW,
                       const float* __restrict__ skipW, const float* __restrict__ resW,
                       const float* __restrict__ last1W, const float* __restrict__ last2W,
                       const float* __restrict__ firstW, const float* __restrict__ firstb,
                       unsigned short* __restrict__ ATb, unsigned short* __restrict__ SRTb,
                       unsigned short* __restrict__ W1b, unsigned short* __restrict__ W2b,
                       float* __restrict__ firstWT) {
    int idx = blockIdx.x * 256 + threadIdx.x;
    const int nAT = NLAYERS * 128 * 288;
    const int nSR = NLAYERS * 128 * 64;
    const int e0 = nAT, e1 = e0 + nSR, e2 = e1 + 4096, e3 = e2 + 16384, e4 = e3 + 16384;
    if (idx < e0) {
        int k = idx % 288;
        int o = (idx / 288) & 127;
        int l = idx / (288 * 128);
        float v = 0.f;
        if (k < 192) v = convW[(((l * 128 + o) * 64) + (k & 63)) * 3 + (k >> 6)];
        else if (k - 192 < 80) v = condW[(l * 128 + o) * 80 + (k - 192)];
        ATb[idx] = f2bf(v);
    } else if (idx < e1) {
        int j = idx - e0;
        int k = j & 63;
        int o2 = (j >> 6) & 127;
        int l = j / (64 * 128);
        float v = (o2 < 64) ? skipW[(l * 64 + o2) * 64 + k]
                            : resW[(l * 64 + (o2 - 64)) * 64 + k];
        SRTb[j] = f2bf(v);
    } else if (idx < e2) {
        W1b[idx - e1] = f2bf(last1W[idx - e1]);
    } else if (idx < e3) {
        W2b[idx - e2] = f2bf(last2W[idx - e2]);
    } else if (idx < e4) {
        int j = idx - e3;
        int xs = j >> 6, c = j & 63;
        firstWT[j] = firstW[c * 256 + xs] + firstb[c];
    }
}

// ---------------------------------------------------------------------------
// Embedding gather -> fp32 master + bf16 mirror (time-major)
// ---------------------------------------------------------------------------
__global__ void k_embed(const int* __restrict__ x, const float* __restrict__ firstWT,
                        float* __restrict__ outF, unsigned short* __restrict__ outH) {
    int idx = blockIdx.x * 256 + threadIdx.x;
    if (idx >= NB * T_LEN * 64) return;
    int c = idx & 63;
    int t = (idx >> 6) & (T_LEN - 1);
    int b = idx >> 20;
    int xs = (t == 0) ? 0 : x[b * T_LEN + t - 1];
    float v = firstWT[xs * 64 + c];
    outF[idx] = v;
    outH[idx] = f2bf(v);
}

// ---------------------------------------------------------------------------
// ConvIn: valid conv, kernel 5, (B,80,68) -> (B,80,64)
// ---------------------------------------------------------------------------
__global__ void k_convin(const float* __restrict__ feat, const float* __restrict__ W,
                         float* __restrict__ f0) {
    int idx = blockIdx.x * 256 + threadIdx.x;
    if (idx >= NB * FCH * 64) return;
    int t = idx & 63;
    int o = (idx >> 6) % FCH;
    int b = idx / (64 * FCH);
    const float* fb = feat + b * FCH * TFRAMES;
    const float* wo = W + o * FCH * 5;
    float acc = 0.f;
    for (int i = 0; i < FCH; ++i) {
        const float* fi = fb + i * TFRAMES + t;
        const float* wi = wo + i * 5;
#pragma unroll
        for (int k = 0; k < 5; ++k) acc += fi[k] * wi[k];
    }
    f0[idx] = acc;
}

// ---------------------------------------------------------------------------
// Upsample stage (x4 repeat + 9-tap smooth), fp32 c-major
// ---------------------------------------------------------------------------
__global__ void k_up(const float* __restrict__ in, float* __restrict__ out,
                     const float* __restrict__ kern, int Tin) {
    int Tout = Tin * 4;
    int idx = blockIdx.x * 256 + threadIdx.x;
    if (idx >= NB * FCH * Tout) return;
    int t = idx % Tout;
    int bc = idx / Tout;
    const float* ib = in + bc * Tin;
    float acc = 0.f;
#pragma unroll
    for (int k = 0; k < 9; ++k) {
        int u = t + k - 4;
        if (u >= 0 && u < Tout) acc += kern[k] * ib[u >> 2];
    }
    out[idx] = acc;
}

// ---------------------------------------------------------------------------
// Last upsample -> bf16 TIME-MAJOR [b][t][96], LDS-staged source frames
// ---------------------------------------------------------------------------
__global__ __launch_bounds__(256)
void k_up_last(const float* __restrict__ in, unsigned short* __restrict__ outH,
               const float* __restrict__ kern) {
    __shared__ float sF[18 * 80];
    const int tid = threadIdx.x;
    const int b  = blockIdx.x >> 8;
    const int t0 = (blockIdx.x & 255) * 64;
    const int fr0 = (t0 >> 2) - 1;

    for (int idx = tid; idx < 18 * 80; idx += 256) {
        int c = idx / 18, fr = idx - c * 18;
        int gfr = fr0 + fr;
        float v = 0.f;
        if (gfr >= 0 && gfr < 4096) v = in[((size_t)b * 80 + c) * 4096 + gfr];
        sF[fr * 80 + c] = v;
    }
    float kr[9];
#pragma unroll
    for (int k = 0; k < 9; ++k) kr[k] = kern[k];
    __syncthreads();

    for (int idx = tid; idx < 64 * 96; idx += 256) {
        int c = idx % 96;
        int t = idx / 96;
        float acc = 0.f;
        if (c < 80) {
            int ubase = t0 + t - 4;
#pragma unroll
            for (int k = 0; k < 9; ++k) {
                int fr = ((ubase + k) >> 2) - fr0;
                acc += kr[k] * sF[fr * 80 + c];
            }
        }
        outH[((size_t)b * T_LEN + t0 + t) * 96 + c] = f2bf(acc);
    }
}

// ---------------------------------------------------------------------------
// STACK KERNEL: 6 fused dilation layers (d=1..32). Output tile 64 cols,
// staged once with 128-col halo; all layers LDS->LDS. Owned-col residual
// fp32 in registers; skip accumulated in registers, RMW'd once per stack.
// flags: bit0 = first stack (skip store, no RMW), bit1 = last stack
// ---------------------------------------------------------------------------
__global__ __launch_bounds__(256, 1)
void k_stack(const float* __restrict__ prevF, const unsigned short* __restrict__ prevH,
             float* __restrict__ nextF, unsigned short* __restrict__ nextH,
             float* __restrict__ skipF, const unsigned short* __restrict__ ffb,
             const unsigned short* __restrict__ ATb, const unsigned short* __restrict__ SRTb,
             const float* __restrict__ convB, const float* __restrict__ skipB,
             const float* __restrict__ resB, int flags)
{
    __shared__ __align__(16) unsigned short s_A[200 * 72];  // residual ping [row][c]
    __shared__ __align__(16) unsigned short s_B[200 * 72];  // residual pong
    __shared__ __align__(16) unsigned short s_Z[192 * 72];  // z [tile*16+col][c]

    const int tid  = threadIdx.x;
    const int b    = blockIdx.x >> 8;
    const int t0   = (blockIdx.x & 255) * 64;
    const int lane = tid & 63;
    const int wv   = tid >> 6;
    const int col  = lane & 15;
    const int quad = lane >> 4;
    const int ch   = 16 * wv + 4 * quad;

    // zero margin rows (0..7) of both buffers
    for (int i = tid; i < 144; i += 256) {
        int bufsel = (i >= 72);
        int j = i - bufsel * 72;
        int r = j / 9, seg = j - r * 9;
        bf16x8 zz = {0, 0, 0, 0, 0, 0, 0, 0};
        *(bf16x8*)((bufsel ? s_B : s_A) + r * 72 + seg * 8) = zz;
    }
    // stage residual (bf16 mirror) rows 8..199 <- abs cols [t0-128, t0+64)
    {
        const unsigned short* hb = prevH + (size_t)b * T_LEN * 64;
        for (int i = tid; i < 192 * 8; i += 256) {
            int r = i >> 3, seg = i & 7;
            int g = t0 - 128 + r;
            bf16x8 v = {0, 0, 0, 0, 0, 0, 0, 0};
            if (g >= 0) v = *(const bf16x8*)(hb + (size_t)g * 64 + seg * 8);
            *(bf16x8*)(s_A + (8 + r) * 72 + seg * 8) = v;
        }
    }
    // own-col fp32 residual + skip accumulator
    f32x4 resReg[4], skipAcc[4];
#pragma unroll
    for (int nt = 0; nt < 4; ++nt) {
        resReg[nt] = *(const f32x4*)(prevF + ((size_t)b * T_LEN + t0 + nt * 16 + col) * 64 + ch);
        skipAcc[nt] = (f32x4){0.f, 0.f, 0.f, 0.f};
    }
    __syncthreads();

    unsigned short* P = s_A;
    unsigned short* Q = s_B;
    const bool lastStack = (flags & 2) != 0;

#pragma unroll 1
    for (int l = 0; l < 6; ++l) {
        const int d  = 1 << l;
        const int ts = (l <= 1) ? 0 : (l == 2 ? 1 : (l == 3 ? 2 : (l == 4 ? 4 : 8)));

        // GEMM1 A-fragments (this layer's weights, L2-resident)
        const unsigned short* AL = ATb + (size_t)l * 128 * 288;
        bf16x8 frA0[9], frA1[9];
#pragma unroll
        for (int ks = 0; ks < 9; ++ks) {
            frA0[ks] = *(const bf16x8*)(AL + (size_t)(16 * wv + col) * 288 + ks * 32 + quad * 8);
            frA1[ks] = *(const bf16x8*)(AL + (size_t)(64 + 16 * wv + col) * 288 + ks * 32 + quad * 8);
        }
        f32x4 cbA = *(const f32x4*)(convB + l * 128 + ch);
        f32x4 cbG = *(const f32x4*)(convB + l * 128 + 64 + ch);

        // ---- GEMM1 + gated activation, per 16-col tile ----
#pragma unroll 1
        for (int tile = ts; tile < 12; ++tile) {
            f32x4 a0 = (f32x4){0.f, 0.f, 0.f, 0.f};
            f32x4 a1 = (f32x4){0.f, 0.f, 0.f, 0.f};
            const int r_out = 8 + tile * 16 + col;
            int gc = t0 - 128 + tile * 16 + col;
            int gcl = gc < 0 ? 0 : gc;
            const unsigned short* fcond = ffb + ((size_t)b * T_LEN + gcl) * 96 + quad * 8;
#pragma unroll
            for (int ks = 0; ks < 9; ++ks) {
                bf16x8 fB;
                if (ks < 6) {
                    int k = ks * 32 + quad * 8;
                    int r_in = r_out - 2 * d + (k >> 6) * d;
                    fB = *(const bf16x8*)(P + r_in * 72 + (k & 63));
                } else {
                    fB = *(const bf16x8*)(fcond + (ks - 6) * 32);
                }
                a0 = __builtin_amdgcn_mfma_f32_16x16x32_bf16(frA0[ks], fB, a0, 0, 0, 0);
                a1 = __builtin_amdgcn_mfma_f32_16x16x32_bf16(frA1[ks], fB, a1, 0, 0, 0);
            }
            unsigned int pk[2];
#pragma unroll
            for (int r2 = 0; r2 < 2; ++r2) {
                float zz[2];
#pragma unroll
                for (int e = 0; e < 2; ++e) {
                    float av = a0[2 * r2 + e] + cbA[2 * r2 + e];
                    float gv = a1[2 * r2 + e] + cbG[2 * r2 + e];
                    float th = 1.f - 2.f * __builtin_amdgcn_rcpf(__expf(2.f * av) + 1.f);
                    float sg = __builtin_amdgcn_rcpf(1.f + __expf(-gv));
                    zz[e] = th * sg;
                }
                pk[r2] = (unsigned int)f2bf(zz[0]) | ((unsigned int)f2bf(zz[1]) << 16);
            }
            unsigned int* zp = (unsigned int*)(s_Z + (tile * 16 + col) * 72 + ch);
            zp[0] = pk[0];
            zp[1] = pk[1];
        }
        __syncthreads();

        // ---- GEMM2: residual + skip ----
        const unsigned short* SL = SRTb + (size_t)l * 128 * 64;
        bf16x8 wk0 = *(const bf16x8*)(SL + (size_t)(16 * wv + col) * 64 + quad * 8);
        bf16x8 wk1 = *(const bf16x8*)(SL + (size_t)(16 * wv + col) * 64 + 32 + quad * 8);
        bf16x8 wr0 = *(const bf16x8*)(SL + (size_t)(64 + 16 * wv + col) * 64 + quad * 8);
        bf16x8 wr1 = *(const bf16x8*)(SL + (size_t)(64 + 16 * wv + col) * 64 + 32 + quad * 8);
        f32x4 rb4 = *(const f32x4*)(resB + l * 64 + ch);
        f32x4 sb4 = *(const f32x4*)(skipB + l * 64 + ch);
        const bool lastLayer = (l == 5);

        if (!(lastLayer && lastStack)) {
#pragma unroll 1
            for (int tile = ts; tile < 12; ++tile) {
                const int zr = (tile * 16 + col) * 72;
                bf16x8 fz0 = *(const bf16x8*)(s_Z + zr + quad * 8);
                bf16x8 fz1 = *(const bf16x8*)(s_Z + zr + 32 + quad * 8);
                const int r_out = 8 + tile * 16 + col;
                f32x4 acc;
                if (tile >= 8) {
                    acc = resReg[tile - 8];
                } else {
                    const unsigned int* pv = (const unsigned int*)(P + r_out * 72 + ch);
                    unsigned int w0 = pv[0], w1 = pv[1];
                    acc[0] = __uint_as_float(w0 << 16);
                    acc[1] = __uint_as_float(w0 & 0xFFFF0000u);
                    acc[2] = __uint_as_float(w1 << 16);
                    acc[3] = __uint_as_float(w1 & 0xFFFF0000u);
                }
                acc = __builtin_amdgcn_mfma_f32_16x16x32_bf16(wr0, fz0, acc, 0, 0, 0);
                acc = __builtin_amdgcn_mfma_f32_16x16x32_bf16(wr1, fz1, acc, 0, 0, 0);
#pragma unroll
                for (int e = 0; e < 4; ++e) acc[e] += rb4[e];
                int g = t0 - 128 + tile * 16 + col;
                if (g < 0) acc = (f32x4){0.f, 0.f, 0.f, 0.f};  // causal: residual is 0 at t<0
                if (tile >= 8) resReg[tile - 8] = acc;
                if (!lastLayer) {
                    unsigned int p01 = (unsigned int)f2bf(acc[0]) | ((unsigned int)f2bf(acc[1]) << 16);
                    unsigned int p23 = (unsigned int)f2bf(acc[2]) | ((unsigned int)f2bf(acc[3]) << 16);
                    unsigned int* qp = (unsigned int*)(Q + r_out * 72 + ch);
                    qp[0] = p01;
                    qp[1] = p23;
                }
            }
        }
        // skip GEMM (own tiles only)
#pragma unroll
        for (int nt = 0; nt < 4; ++nt) {
            const int zr = ((8 + nt) * 16 + col) * 72;
            bf16x8 fz0 = *(const bf16x8*)(s_Z + zr + quad * 8);
            bf16x8 fz1 = *(const bf16x8*)(s_Z + zr + 32 + quad * 8);
            f32x4 s = (f32x4){0.f, 0.f, 0.f, 0.f};
            s = __builtin_amdgcn_mfma_f32_16x16x32_bf16(wk0, fz0, s, 0, 0, 0);
            s = __builtin_amdgcn_mfma_f32_16x16x32_bf16(wk1, fz1, s, 0, 0, 0);
#pragma unroll
            for (int e = 0; e < 4; ++e) skipAcc[nt][e] += s[e] + sb4[e];
        }
        __syncthreads();
        unsigned short* tmp = P; P = Q; Q = tmp;
    }

    // epilogue
    if (!lastStack) {
#pragma unroll
        for (int nt = 0; nt < 4; ++nt) {
            size_t base = ((size_t)b * T_LEN + t0 + nt * 16 + col) * 64 + ch;
            *(f32x4*)(nextF + base) = resReg[nt];
            unsigned int p01 = (unsigned int)f2bf(resReg[nt][0]) | ((unsigned int)f2bf(resReg[nt][1]) << 16);
            unsigned int p23 = (unsigned int)f2bf(resReg[nt][2]) | ((unsigned int)f2bf(resReg[nt][3]) << 16);
            unsigned int* hp = (unsigned int*)(nextH + base);
            hp[0] = p01;
            hp[1] = p23;
        }
    }
#pragma unroll
    for (int nt = 0; nt < 4; ++nt) {
        size_t base = ((size_t)b * T_LEN + t0 + nt * 16 + col) * 64 + ch;
        if (flags & 1) {
            *(f32x4*)(skipF + base) = skipAcc[nt];
        } else {
            f32x4 s = *(const f32x4*)(skipF + base);
#pragma unroll
            for (int e = 0; e < 4; ++e) s[e] += skipAcc[nt][e];
            *(f32x4*)(skipF + base) = s;
        }
    }
}

// ---------------------------------------------------------------------------
// Tail: relu(skip) -> last1 -> relu -> last2 -> out (fp32 c-major)
// ---------------------------------------------------------------------------
__global__ __launch_bounds__(256)
void k_tail2(const float* __restrict__ skipF,
             const unsigned short* __restrict__ W1b, const float* __restrict__ b1,
             const unsigned short* __restrict__ W2b, const float* __restrict__ b2,
             float* __restrict__ out)
{
    __shared__ __align__(16) unsigned short s_S[64 * 72];
    __shared__ __align__(16) unsigned short s_H[64 * 72];
    const int tid = threadIdx.x;
    const int b   = blockIdx.x >> 8;
    const int t0  = (blockIdx.x & 255) * 64;
    const int lane = tid & 63, wv = tid >> 6, col = lane & 15, quad = lane >> 4;

    const float* sp = skipF + (((size_t)b * T_LEN) + t0) * 64;
    for (int i = tid; i < 64 * 32; i += 256) {
        int t = i >> 5, c2 = i & 31;
        float v0 = fmaxf(sp[t * 64 + 2 * c2], 0.f);
        float v1 = fmaxf(sp[t * 64 + 2 * c2 + 1], 0.f);
        *(unsigned int*)(s_S + t * 72 + 2 * c2) =
            (unsigned int)f2bf(v0) | ((unsigned int)f2bf(v1) << 16);
    }
    __syncthreads();

    // last1
    f32x4 aL[4];
#pragma unroll
    for (int nt = 0; nt < 4; ++nt) aL[nt] = (f32x4){0.f, 0.f, 0.f, 0.f};
#pragma unroll
    for (int ks = 0; ks < 2; ++ks) {
        bf16x8 fw = *(const bf16x8*)(W1b + (size_t)(16 * wv + col) * 64 + ks * 32 + quad * 8);
#pragma unroll
        for (int nt = 0; nt < 4; ++nt) {
            bf16x8 fz = *(const bf16x8*)(s_S + (nt * 16 + col) * 72 + ks * 32 + quad * 8);
            aL[nt] = __builtin_amdgcn_mfma_f32_16x16x32_bf16(fw, fz, aL[nt], 0, 0, 0);
        }
    }
    f32x4 bb1 = *(const f32x4*)(b1 + 16 * wv + 4 * quad);
#pragma unroll
    for (int nt = 0; nt < 4; ++nt) {
        float h0 = fmaxf(aL[nt][0] + bb1[0], 0.f), h1 = fmaxf(aL[nt][1] + bb1[1], 0.f);
        float h2 = fmaxf(aL[nt][2] + bb1[2], 0.f), h3 = fmaxf(aL[nt][3] + bb1[3], 0.f);
        unsigned int* hp = (unsigned int*)(s_H + (nt * 16 + col) * 72 + 16 * wv + 4 * quad);
        hp[0] = (unsigned int)f2bf(h0) | ((unsigned int)f2bf(h1) << 16);
        hp[1] = (unsigned int)f2bf(h2) | ((unsigned int)f2bf(h3) << 16);
    }
    __syncthreads();

    // last2
    f32x4 aO[4][4];
#pragma unroll
    for (int p = 0; p < 4; ++p)
#pragma unroll
        for (int nt = 0; nt < 4; ++nt) aO[p][nt] = (f32x4){0.f, 0.f, 0.f, 0.f};
#pragma unroll
    for (int ks = 0; ks < 2; ++ks) {
#pragma unroll
        for (int nt = 0; nt < 4; ++nt) {
            bf16x8 fz = *(const bf16x8*)(s_H + (nt * 16 + col) * 72 + ks * 32 + quad * 8);
#pragma unroll
            for (int p = 0; p < 4; ++p) {
                bf16x8 fw = *(const bf16x8*)(W2b + (size_t)(16 * (wv + 4 * p) + col) * 64
                                             + ks * 32 + quad * 8);
                aO[p][nt] = __builtin_amdgcn_mfma_f32_16x16x32_bf16(fw, fz, aO[p][nt], 0, 0, 0);
            }
        }
    }
#pragma unroll
    for (int p = 0; p < 4; ++p) {
        int o0 = 16 * (wv + 4 * p) + 4 * quad;
        f32x4 bb2 = *(const f32x4*)(b2 + o0);
#pragma unroll
        for (int nt = 0; nt < 4; ++nt) {
            int t = t0 + nt * 16 + col;
#pragma unroll
            for (int e = 0; e < 4; ++e)
                out[((size_t)b * 256 + o0 + e) * T_LEN + t] = aO[p][nt][e] + bb2[e];
        }
    }
}

// ---------------------------------------------------------------------------
extern "C" void kernel_launch(void* const* d_in, const int* in_sizes, int n_in,
                              void* d_out, int out_size, void* d_ws, size_t ws_size,
                              hipStream_t stream) {
    const int*   x       = (const int*)  d_in[0];
    const float* feature = (const float*)d_in[1];
    const float* firstW  = (const float*)d_in[2];
    const float* firstb  = (const float*)d_in[3];
    const float* convW   = (const float*)d_in[4];
    const float* convB   = (const float*)d_in[5];
    const float* condW   = (const float*)d_in[6];
    const float* skipW   = (const float*)d_in[7];
    const float* skipB   = (const float*)d_in[8];
    const float* resW    = (const float*)d_in[9];
    const float* resB    = (const float*)d_in[10];
    const float* last1W  = (const float*)d_in[11];
    const float* last1b  = (const float*)d_in[12];
    const float* last2W  = (const float*)d_in[13];
    const float* last2b  = (const float*)d_in[14];
    const float* convinW = (const float*)d_in[15];
    const float* upK     = (const float*)d_in[16];

    float* ws = (float*)d_ws;
    float* f0      = ws;                       // 10240
    float* f1      = f0 + 10240;               // 40960
    float* f2      = f1 + 40960;               // 163840
    float* f3      = f2 + 163840;              // 655360
    float* firstWT = f3 + 655360;              // 16384
    float* resA    = firstWT + 16384;          // 2097152
    float* resB_   = resA + 2097152;           // 2097152
    float* skipF   = resB_ + 2097152;          // 2097152
    unsigned short* mirA = (unsigned short*)(skipF + 2097152);  // 2097152
    unsigned short* mirB = mirA + 2097152;                      // 2097152
    unsigned short* ffb  = mirB + 2097152;                      // 3145728
    unsigned short* ATb  = ffb + 3145728;                       // 884736
    unsigned short* SRTb = ATb + 884736;                        // 196608
    unsigned short* W1b  = SRTb + 196608;                       // 4096
    unsigned short* W2b  = W1b + 4096;                          // 16384

    int n;
    n = NLAYERS * 128 * 288 + NLAYERS * 128 * 64 + 4096 + 16384 + 16384;
    k_pack<<<(n + 255) / 256, 256, 0, stream>>>(convW, condW, skipW, resW, last1W, last2W,
                                                firstW, firstb, ATb, SRTb, W1b, W2b, firstWT);
    n = NB * FCH * 64;
    k_convin<<<(n + 255) / 256, 256, 0, stream>>>(feature, convinW, f0);
    k_up<<<(NB * FCH * 256 + 255) / 256, 256, 0, stream>>>(f0, f1, upK + 0, 64);
    k_up<<<(NB * FCH * 1024 + 255) / 256, 256, 0, stream>>>(f1, f2, upK + 9, 256);
    k_up<<<(NB * FCH * 4096 + 255) / 256, 256, 0, stream>>>(f2, f3, upK + 18, 1024);
    k_up_last<<<NB * 256, 256, 0, stream>>>(f3, ffb, upK + 27);
    n = NB * T_LEN * 64;
    k_embed<<<(n + 255) / 256, 256, 0, stream>>>(x, firstWT, resA, mirA);

    float* poF = resA;          float* pnF = resB_;
    unsigned short* poH = mirA; unsigned short* pnH = mirB;
    for (int s = 0; s < 4; ++s) {
        int flags = (s == 0 ? 1 : 0) | (s == 3 ? 2 : 0);
        k_stack<<<NB * 256, 256, 0, stream>>>(
            poF, poH, pnF, pnH, skipF, ffb,
            ATb + (size_t)s * 6 * 128 * 288, SRTb + (size_t)s * 6 * 128 * 64,
            convB + s * 6 * 128, skipB + s * 6 * 64, resB + s * 6 * 64, flags);
        float* tf = poF; poF = pnF; pnF = tf;
        unsigned short* th = poH; poH = pnH; pnH = th;
    }

    k_tail2<<<NB * 256, 256, 0, stream>>>(skipF, W1b, last1b, W2b, last2b, (float*)d_out);
}

// Round 8
// 393.236 us; speedup vs baseline: 1.5742x; 1.5742x over previous
//
#include <hip/hip_runtime.h>
#include <math.h>

#define T_LEN   16384
#define NB      2
#define FCH     80
#define NLAYERS 24
#define TFRAMES 68

typedef __attribute__((ext_vector_type(8))) short bf16x8;
typedef __attribute__((ext_vector_type(4))) float f32x4;

static __device__ inline unsigned short f2bf(float f) {
    unsigned int u = __float_as_uint(f);
    unsigned int r = (u + 0x7FFFu + ((u >> 16) & 1u)) >> 16;
    return (unsigned short)r;
}

// ---------------------------------------------------------------------------
// Pack: bf16 weight layouts + firstWT (transposed embedding table, bias folded)
// ---------------------------------------------------------------------------
__global__ void k_pack(const float* __restrict__ convW, const float* __restrict__ condW,
                       const float* __restrict__ skipW, const float* __restrict__ resW,
                       const float* __restrict__ last1W, const float* __restrict__ last2W,
                       const float* __restrict__ firstW, const float* __restrict__ firstb,
                       unsigned short* __restrict__ ATb, unsigned short* __restrict__ SRTb,
                       unsigned short* __restrict__ W1b, unsigned short* __restrict__ W2b,
                       float* __restrict__ firstWT) {
    int idx = blockIdx.x * 256 + threadIdx.x;
    const int nAT = NLAYERS * 128 * 288;
    const int nSR = NLAYERS * 128 * 64;
    const int e0 = nAT, e1 = e0 + nSR, e2 = e1 + 4096, e3 = e2 + 16384, e4 = e3 + 16384;
    if (idx < e0) {
        int k = idx % 288;
        int o = (idx / 288) & 127;
        int l = idx / (288 * 128);
        float v = 0.f;
        if (k < 192) v = convW[(((l * 128 + o) * 64) + (k & 63)) * 3 + (k >> 6)];
        else if (k - 192 < 80) v = condW[(l * 128 + o) * 80 + (k - 192)];
        ATb[idx] = f2bf(v);
    } else if (idx < e1) {
        int j = idx - e0;
        int k = j & 63;
        int o2 = (j >> 6) & 127;
        int l = j / (64 * 128);
        float v = (o2 < 64) ? skipW[(l * 64 + o2) * 64 + k]
                            : resW[(l * 64 + (o2 - 64)) * 64 + k];
        SRTb[j] = f2bf(v);
    } else if (idx < e2) {
        W1b[idx - e1] = f2bf(last1W[idx - e1]);
    } else if (idx < e3) {
        W2b[idx - e2] = f2bf(last2W[idx - e2]);
    } else if (idx < e4) {
        int j = idx - e3;
        int xs = j >> 6, c = j & 63;
        firstWT[j] = firstW[c * 256 + xs] + firstb[c];
    }
}

// ---------------------------------------------------------------------------
// ConvIn: valid conv, kernel 5, (B,80,68) -> (B,80,64)
// ---------------------------------------------------------------------------
__global__ void k_convin(const float* __restrict__ feat, const float* __restrict__ W,
                         float* __restrict__ f0) {
    int idx = blockIdx.x * 256 + threadIdx.x;
    if (idx >= NB * FCH * 64) return;
    int t = idx & 63;
    int o = (idx >> 6) % FCH;
    int b = idx / (64 * FCH);
    const float* fb = feat + b * FCH * TFRAMES;
    const float* wo = W + o * FCH * 5;
    float acc = 0.f;
    for (int i = 0; i < FCH; ++i) {
        const float* fi = fb + i * TFRAMES + t;
        const float* wi = wo + i * 5;
#pragma unroll
        for (int k = 0; k < 5; ++k) acc += fi[k] * wi[k];
    }
    f0[idx] = acc;
}

// ---------------------------------------------------------------------------
// Upsample stage (x4 repeat + 9-tap smooth), fp32 c-major
// ---------------------------------------------------------------------------
__global__ void k_up(const float* __restrict__ in, float* __restrict__ out,
                     const float* __restrict__ kern, int Tin) {
    int Tout = Tin * 4;
    int idx = blockIdx.x * 256 + threadIdx.x;
    if (idx >= NB * FCH * Tout) return;
    int t = idx % Tout;
    int bc = idx / Tout;
    const float* ib = in + bc * Tin;
    float acc = 0.f;
#pragma unroll
    for (int k = 0; k < 9; ++k) {
        int u = t + k - 4;
        if (u >= 0 && u < Tout) acc += kern[k] * ib[u >> 2];
    }
    out[idx] = acc;
}

// ---------------------------------------------------------------------------
// Last upsample -> bf16 TIME-MAJOR [b][t][96], LDS-staged source frames
// ---------------------------------------------------------------------------
__global__ __launch_bounds__(256)
void k_up_last(const float* __restrict__ in, unsigned short* __restrict__ outH,
               const float* __restrict__ kern) {
    __shared__ float sF[18 * 80];
    const int tid = threadIdx.x;
    const int b  = blockIdx.x >> 8;
    const int t0 = (blockIdx.x & 255) * 64;
    const int fr0 = (t0 >> 2) - 1;

    for (int idx = tid; idx < 18 * 80; idx += 256) {
        int c = idx / 18, fr = idx - c * 18;
        int gfr = fr0 + fr;
        float v = 0.f;
        if (gfr >= 0 && gfr < 4096) v = in[((size_t)b * 80 + c) * 4096 + gfr];
        sF[fr * 80 + c] = v;
    }
    float kr[9];
#pragma unroll
    for (int k = 0; k < 9; ++k) kr[k] = kern[k];
    __syncthreads();

    for (int idx = tid; idx < 64 * 96; idx += 256) {
        int c = idx % 96;
        int t = idx / 96;
        float acc = 0.f;
        if (c < 80) {
            int ubase = t0 + t - 4;
#pragma unroll
            for (int k = 0; k < 9; ++k) {
                int fr = ((ubase + k) >> 2) - fr0;
                acc += kr[k] * sF[fr * 80 + c];
            }
        }
        outH[((size_t)b * T_LEN + t0 + t) * 96 + c] = f2bf(acc);
    }
}

// ---------------------------------------------------------------------------
// STACK KERNEL v2.1: 6 fused dilation layers, 512 threads (8 waves), tile=128,
// halo=128, grid 256 blocks = 1/CU one round. Embed fused into stack0,
// tail (skip->relu->last1->relu->last2) fused into stack3.
// flags: bit0 = first stack, bit1 = last stack
// FIX vs v2: res-wave halo loop starts at ts_out[l] (not ts_out[l+1]) — layer
// l+1's GEMM1 back-reaches 2*d below its first tile, so layer l must write
// every tile it computed z for. (R7 bug: stale tile-0 rows fed layer 2.)
// ---------------------------------------------------------------------------
__global__ __launch_bounds__(512, 1)
void k_stack(const int* __restrict__ x, const float* __restrict__ firstWT,
             const float* __restrict__ prevF, const unsigned short* __restrict__ prevH,
             float* __restrict__ nextF, unsigned short* __restrict__ nextH,
             float* __restrict__ skipF, const unsigned short* __restrict__ ffb,
             const unsigned short* __restrict__ ATb, const unsigned short* __restrict__ SRTb,
             const float* __restrict__ convB, const float* __restrict__ skipB,
             const float* __restrict__ resB,
             const unsigned short* __restrict__ W1b, const float* __restrict__ b1,
             const unsigned short* __restrict__ W2b, const float* __restrict__ b2,
             float* __restrict__ outp, int flags)
{
    __shared__ __align__(16) unsigned short s_A[264 * 72];  // residual ping [row][c]
    __shared__ __align__(16) unsigned short s_B[264 * 72];  // residual pong
    __shared__ __align__(16) unsigned short s_Z[256 * 72];  // z / tail staging

    const int tid  = threadIdx.x;
    const int b    = blockIdx.x >> 7;
    const int t0   = (blockIdx.x & 127) * 128;
    const int lane = tid & 63;
    const int wv   = tid >> 6;          // 0..7
    const int col  = lane & 15;
    const int quad = lane >> 4;
    const int pair = wv & 3;            // GEMM1 gate pair
    const int par  = wv >> 2;           // col-tile parity
    const int chA  = 16 * pair + 4 * quad;          // a-channel base (GEMM1)
    const int srm  = (wv < 4) ? wv : (wv - 4);      // GEMM2 ch-tile
    const int chS  = 16 * srm + 4 * quad;           // skip/res channel base
    const bool firstStack = (flags & 1) != 0;
    const bool lastStack  = (flags & 2) != 0;

    // output-tile start (tile units) per layer; [6] sentinel
    const int ts_out[7] = {0, 0, 1, 2, 4, 8, 8};

    // zero margin rows 0..7 of both buffers
    for (int i = tid; i < 144; i += 512) {
        int bufsel = (i >= 72);
        int j = i - bufsel * 72;
        int r = j / 9, seg = j - r * 9;
        bf16x8 zz = {0, 0, 0, 0, 0, 0, 0, 0};
        *(bf16x8*)((bufsel ? s_B : s_A) + r * 72 + seg * 8) = zz;
    }
    // stage residual rows 8..263 <- abs cols [t0-128, t0+128)
    if (firstStack) {
        for (int i = tid; i < 256 * 8; i += 512) {
            int r = i >> 3, seg = i & 7;
            int g = t0 - 128 + r;
            bf16x8 v = {0, 0, 0, 0, 0, 0, 0, 0};
            if (g >= 0) {
                int xs = (g == 0) ? 0 : x[b * T_LEN + g - 1];
                const float* p = firstWT + xs * 64 + seg * 8;
                f32x4 a0 = *(const f32x4*)p;
                f32x4 a1 = *(const f32x4*)(p + 4);
                v[0] = (short)f2bf(a0[0]); v[1] = (short)f2bf(a0[1]);
                v[2] = (short)f2bf(a0[2]); v[3] = (short)f2bf(a0[3]);
                v[4] = (short)f2bf(a1[0]); v[5] = (short)f2bf(a1[1]);
                v[6] = (short)f2bf(a1[2]); v[7] = (short)f2bf(a1[3]);
            }
            *(bf16x8*)(s_A + (8 + r) * 72 + seg * 8) = v;
        }
    } else {
        const unsigned short* hb = prevH + (size_t)b * T_LEN * 64;
        for (int i = tid; i < 256 * 8; i += 512) {
            int r = i >> 3, seg = i & 7;
            int g = t0 - 128 + r;
            bf16x8 v = {0, 0, 0, 0, 0, 0, 0, 0};
            if (g >= 0) v = *(const bf16x8*)(hb + (size_t)g * 64 + seg * 8);
            *(bf16x8*)(s_A + (8 + r) * 72 + seg * 8) = v;
        }
    }

    // per-wave persistent state
    f32x4 resReg[8];    // res waves (wv>=4): fp32 residual, owned tiles
    f32x4 skipAcc[8];   // skip waves (wv<4): skip accumulator, owned tiles
#pragma unroll
    for (int i = 0; i < 8; ++i) skipAcc[i] = (f32x4){0.f, 0.f, 0.f, 0.f};
    if (wv >= 4) {
        if (firstStack) {
#pragma unroll
            for (int i = 0; i < 8; ++i) {
                int t = t0 + i * 16 + col;
                int xs = (t == 0) ? 0 : x[b * T_LEN + t - 1];
                resReg[i] = *(const f32x4*)(firstWT + xs * 64 + chS);
            }
        } else {
#pragma unroll
            for (int i = 0; i < 8; ++i)
                resReg[i] = *(const f32x4*)(prevF +
                              ((size_t)b * T_LEN + t0 + i * 16 + col) * 64 + chS);
        }
    }
    __syncthreads();

    unsigned short* P = s_A;
    unsigned short* Q = s_B;

#pragma unroll 1
    for (int l = 0; l < 6; ++l) {
        const int d  = 1 << l;
        const int ts = ts_out[l];

        // GEMM1 A-fragments for this wave's gate pair
        const unsigned short* AL = ATb + (size_t)l * 128 * 288;
        bf16x8 frA0[9], frA1[9];
#pragma unroll
        for (int ks = 0; ks < 9; ++ks) {
            frA0[ks] = *(const bf16x8*)(AL + (size_t)(16 * pair + col) * 288 + ks * 32 + quad * 8);
            frA1[ks] = *(const bf16x8*)(AL + (size_t)(64 + 16 * pair + col) * 288 + ks * 32 + quad * 8);
        }
        f32x4 cbA = *(const f32x4*)(convB + l * 128 + chA);
        f32x4 cbG = *(const f32x4*)(convB + l * 128 + 64 + chA);

        // ---- GEMM1 + gated activation ----
#pragma unroll 1
        for (int tl = ts; tl < 16; ++tl) {
            if ((tl & 1) != par) continue;
            const int r_base = 8 + tl * 16 + col;
            int g = t0 - 128 + tl * 16 + col;
            int gcl = g < 0 ? 0 : g;
            const unsigned short* fc = ffb + ((size_t)b * T_LEN + gcl) * 96 + quad * 8;
            bf16x8 f6 = *(const bf16x8*)(fc);
            bf16x8 f7 = *(const bf16x8*)(fc + 32);
            bf16x8 f8 = *(const bf16x8*)(fc + 64);
            f32x4 a0 = (f32x4){0.f, 0.f, 0.f, 0.f};
            f32x4 a1 = (f32x4){0.f, 0.f, 0.f, 0.f};
#pragma unroll
            for (int ks = 0; ks < 6; ++ks) {
                int r_in = r_base - 2 * d + (ks >> 1) * d;
                bf16x8 fB = *(const bf16x8*)(P + r_in * 72 + (ks & 1) * 32 + quad * 8);
                a0 = __builtin_amdgcn_mfma_f32_16x16x32_bf16(frA0[ks], fB, a0, 0, 0, 0);
                a1 = __builtin_amdgcn_mfma_f32_16x16x32_bf16(frA1[ks], fB, a1, 0, 0, 0);
            }
            a0 = __builtin_amdgcn_mfma_f32_16x16x32_bf16(frA0[6], f6, a0, 0, 0, 0);
            a1 = __builtin_amdgcn_mfma_f32_16x16x32_bf16(frA1[6], f6, a1, 0, 0, 0);
            a0 = __builtin_amdgcn_mfma_f32_16x16x32_bf16(frA0[7], f7, a0, 0, 0, 0);
            a1 = __builtin_amdgcn_mfma_f32_16x16x32_bf16(frA1[7], f7, a1, 0, 0, 0);
            a0 = __builtin_amdgcn_mfma_f32_16x16x32_bf16(frA0[8], f8, a0, 0, 0, 0);
            a1 = __builtin_amdgcn_mfma_f32_16x16x32_bf16(frA1[8], f8, a1, 0, 0, 0);

            unsigned int pk[2];
#pragma unroll
            for (int r2 = 0; r2 < 2; ++r2) {
                float zz[2];
#pragma unroll
                for (int e = 0; e < 2; ++e) {
                    float av = a0[2 * r2 + e] + cbA[2 * r2 + e];
                    float gv = a1[2 * r2 + e] + cbG[2 * r2 + e];
                    float th = 1.f - 2.f * __builtin_amdgcn_rcpf(__expf(2.f * av) + 1.f);
                    float sg = __builtin_amdgcn_rcpf(1.f + __expf(-gv));
                    zz[e] = th * sg;
                }
                pk[r2] = (unsigned int)f2bf(zz[0]) | ((unsigned int)f2bf(zz[1]) << 16);
            }
            unsigned int* zp = (unsigned int*)(s_Z + (tl * 16 + col) * 72 + chA);
            zp[0] = pk[0];
            zp[1] = pk[1];
        }
        __syncthreads();

        // ---- GEMM2 ----
        const unsigned short* SL = SRTb + (size_t)l * 128 * 64;
        if (wv < 4) {
            // skip: owned tiles only
            bf16x8 wk0 = *(const bf16x8*)(SL + (size_t)(16 * srm + col) * 64 + quad * 8);
            bf16x8 wk1 = *(const bf16x8*)(SL + (size_t)(16 * srm + col) * 64 + 32 + quad * 8);
            f32x4 sb4 = *(const f32x4*)(skipB + l * 64 + chS);
#pragma unroll
            for (int i = 0; i < 8; ++i) {
                const int zr = ((8 + i) * 16 + col) * 72;
                bf16x8 fz0 = *(const bf16x8*)(s_Z + zr + quad * 8);
                bf16x8 fz1 = *(const bf16x8*)(s_Z + zr + 32 + quad * 8);
                f32x4 s = (f32x4){0.f, 0.f, 0.f, 0.f};
                s = __builtin_amdgcn_mfma_f32_16x16x32_bf16(wk0, fz0, s, 0, 0, 0);
                s = __builtin_amdgcn_mfma_f32_16x16x32_bf16(wk1, fz1, s, 0, 0, 0);
#pragma unroll
                for (int e = 0; e < 4; ++e) skipAcc[i][e] += s[e] + sb4[e];
            }
        } else {
            // res: halo tiles (from ts_out[l] — every tile z was computed for)
            bf16x8 wr0 = *(const bf16x8*)(SL + (size_t)(64 + 16 * srm + col) * 64 + quad * 8);
            bf16x8 wr1 = *(const bf16x8*)(SL + (size_t)(64 + 16 * srm + col) * 64 + 32 + quad * 8);
            f32x4 rb4 = *(const f32x4*)(resB + l * 64 + chS);
#pragma unroll 1
            for (int tl = ts; tl < 8; ++tl) {
                const int zr = (tl * 16 + col) * 72;
                bf16x8 fz0 = *(const bf16x8*)(s_Z + zr + quad * 8);
                bf16x8 fz1 = *(const bf16x8*)(s_Z + zr + 32 + quad * 8);
                const int row = 8 + tl * 16 + col;
                const unsigned int* pv = (const unsigned int*)(P + row * 72 + chS);
                unsigned int w0 = pv[0], w1 = pv[1];
                f32x4 acc;
                acc[0] = __uint_as_float(w0 << 16);
                acc[1] = __uint_as_float(w0 & 0xFFFF0000u);
                acc[2] = __uint_as_float(w1 << 16);
                acc[3] = __uint_as_float(w1 & 0xFFFF0000u);
                acc = __builtin_amdgcn_mfma_f32_16x16x32_bf16(wr0, fz0, acc, 0, 0, 0);
                acc = __builtin_amdgcn_mfma_f32_16x16x32_bf16(wr1, fz1, acc, 0, 0, 0);
#pragma unroll
                for (int e = 0; e < 4; ++e) acc[e] += rb4[e];
                int g = t0 - 128 + tl * 16 + col;
                if (g < 0) acc = (f32x4){0.f, 0.f, 0.f, 0.f};
                unsigned int p01 = (unsigned int)f2bf(acc[0]) | ((unsigned int)f2bf(acc[1]) << 16);
                unsigned int p23 = (unsigned int)f2bf(acc[2]) | ((unsigned int)f2bf(acc[3]) << 16);
                unsigned int* qp = (unsigned int*)(Q + row * 72 + chS);
                qp[0] = p01;
                qp[1] = p23;
            }
            if (!(lastStack && l == 5)) {
#pragma unroll
                for (int i = 0; i < 8; ++i) {
                    const int zr = ((8 + i) * 16 + col) * 72;
                    bf16x8 fz0 = *(const bf16x8*)(s_Z + zr + quad * 8);
                    bf16x8 fz1 = *(const bf16x8*)(s_Z + zr + 32 + quad * 8);
                    f32x4 acc = resReg[i];
                    acc = __builtin_amdgcn_mfma_f32_16x16x32_bf16(wr0, fz0, acc, 0, 0, 0);
                    acc = __builtin_amdgcn_mfma_f32_16x16x32_bf16(wr1, fz1, acc, 0, 0, 0);
#pragma unroll
                    for (int e = 0; e < 4; ++e) acc[e] += rb4[e];
                    resReg[i] = acc;
                    if (l < 5) {
                        const int row = 8 + (8 + i) * 16 + col;
                        unsigned int p01 = (unsigned int)f2bf(acc[0]) | ((unsigned int)f2bf(acc[1]) << 16);
                        unsigned int p23 = (unsigned int)f2bf(acc[2]) | ((unsigned int)f2bf(acc[3]) << 16);
                        unsigned int* qp = (unsigned int*)(Q + row * 72 + chS);
                        qp[0] = p01;
                        qp[1] = p23;
                    }
                }
            }
        }
        __syncthreads();
        unsigned short* tmp = P; P = Q; Q = tmp;
    }

    // ---------------- epilogue ----------------
    if (!lastStack) {
        if (wv >= 4) {
#pragma unroll
            for (int i = 0; i < 8; ++i) {
                size_t base = ((size_t)b * T_LEN + t0 + i * 16 + col) * 64 + chS;
                *(f32x4*)(nextF + base) = resReg[i];
                unsigned int p01 = (unsigned int)f2bf(resReg[i][0]) | ((unsigned int)f2bf(resReg[i][1]) << 16);
                unsigned int p23 = (unsigned int)f2bf(resReg[i][2]) | ((unsigned int)f2bf(resReg[i][3]) << 16);
                unsigned int* hp = (unsigned int*)(nextH + base);
                hp[0] = p01;
                hp[1] = p23;
            }
        } else {
#pragma unroll
            for (int i = 0; i < 8; ++i) {
                size_t base = ((size_t)b * T_LEN + t0 + i * 16 + col) * 64 + chS;
                if (firstStack) {
                    *(f32x4*)(skipF + base) = skipAcc[i];
                } else {
                    f32x4 s = *(const f32x4*)(skipF + base);
#pragma unroll
                    for (int e = 0; e < 4; ++e) s[e] += skipAcc[i][e];
                    *(f32x4*)(skipF + base) = s;
                }
            }
        }
        return;
    }

    // ---------------- fused tail (last stack) ----------------
    unsigned short* s_S = s_Z;
    unsigned short* s_H = s_Z + 128 * 72;
    if (wv < 4) {
#pragma unroll
        for (int i = 0; i < 8; ++i) {
            size_t base = ((size_t)b * T_LEN + t0 + i * 16 + col) * 64 + chS;
            f32x4 s = *(const f32x4*)(skipF + base);
            float v0 = fmaxf(s[0] + skipAcc[i][0], 0.f);
            float v1 = fmaxf(s[1] + skipAcc[i][1], 0.f);
            float v2 = fmaxf(s[2] + skipAcc[i][2], 0.f);
            float v3 = fmaxf(s[3] + skipAcc[i][3], 0.f);
            unsigned int* sp = (unsigned int*)(s_S + (i * 16 + col) * 72 + chS);
            sp[0] = (unsigned int)f2bf(v0) | ((unsigned int)f2bf(v1) << 16);
            sp[1] = (unsigned int)f2bf(v2) | ((unsigned int)f2bf(v3) << 16);
        }
    }
    __syncthreads();

    // last1: h2 = relu(W1 @ relu(skip) + b1)
    {
        const int m1 = wv & 3;
        const int q1 = wv >> 2;
        bf16x8 fw0 = *(const bf16x8*)(W1b + (size_t)(16 * m1 + col) * 64 + quad * 8);
        bf16x8 fw1 = *(const bf16x8*)(W1b + (size_t)(16 * m1 + col) * 64 + 32 + quad * 8);
        f32x4 bb1 = *(const f32x4*)(b1 + 16 * m1 + 4 * quad);
#pragma unroll
        for (int i = 0; i < 8; ++i) {
            if ((i & 1) != q1) continue;
            const int zr = (i * 16 + col) * 72;
            bf16x8 fz0 = *(const bf16x8*)(s_S + zr + quad * 8);
            bf16x8 fz1 = *(const bf16x8*)(s_S + zr + 32 + quad * 8);
            f32x4 a = (f32x4){0.f, 0.f, 0.f, 0.f};
            a = __builtin_amdgcn_mfma_f32_16x16x32_bf16(fw0, fz0, a, 0, 0, 0);
            a = __builtin_amdgcn_mfma_f32_16x16x32_bf16(fw1, fz1, a, 0, 0, 0);
            float h0 = fmaxf(a[0] + bb1[0], 0.f), h1 = fmaxf(a[1] + bb1[1], 0.f);
            float h2 = fmaxf(a[2] + bb1[2], 0.f), h3 = fmaxf(a[3] + bb1[3], 0.f);
            unsigned int* hp = (unsigned int*)(s_H + (i * 16 + col) * 72 + 16 * m1 + 4 * quad);
            hp[0] = (unsigned int)f2bf(h0) | ((unsigned int)f2bf(h1) << 16);
            hp[1] = (unsigned int)f2bf(h2) | ((unsigned int)f2bf(h3) << 16);
        }
    }
    __syncthreads();

    // last2: out = W2 @ h2 + b2  (fp32 c-major)
#pragma unroll
    for (int p2 = 0; p2 < 2; ++p2) {
        const int m2 = wv + 8 * p2;
        bf16x8 fw0 = *(const bf16x8*)(W2b + (size_t)(16 * m2 + col) * 64 + quad * 8);
        bf16x8 fw1 = *(const bf16x8*)(W2b + (size_t)(16 * m2 + col) * 64 + 32 + quad * 8);
        f32x4 bb2 = *(const f32x4*)(b2 + 16 * m2 + 4 * quad);
#pragma unroll
        for (int i = 0; i < 8; ++i) {
            const int zr = (i * 16 + col) * 72;
            bf16x8 fz0 = *(const bf16x8*)(s_H + zr + quad * 8);
            bf16x8 fz1 = *(const bf16x8*)(s_H + zr + 32 + quad * 8);
            f32x4 a = (f32x4){0.f, 0.f, 0.f, 0.f};
            a = __builtin_amdgcn_mfma_f32_16x16x32_bf16(fw0, fz0, a, 0, 0, 0);
            a = __builtin_amdgcn_mfma_f32_16x16x32_bf16(fw1, fz1, a, 0, 0, 0);
            int t = t0 + i * 16 + col;
            int o0 = 16 * m2 + 4 * quad;
#pragma unroll
            for (int e = 0; e < 4; ++e)
                outp[((size_t)b * 256 + o0 + e) * T_LEN + t] = a[e] + bb2[e];
        }
    }
}

// ---------------------------------------------------------------------------
extern "C" void kernel_launch(void* const* d_in, const int* in_sizes, int n_in,
                              void* d_out, int out_size, void* d_ws, size_t ws_size,
                              hipStream_t stream) {
    const int*   x       = (const int*)  d_in[0];
    const float* feature = (const float*)d_in[1];
    const float* firstW  = (const float*)d_in[2];
    const float* firstb  = (const float*)d_in[3];
    const float* convW   = (const float*)d_in[4];
    const float* convB   = (const float*)d_in[5];
    const float* condW   = (const float*)d_in[6];
    const float* skipW   = (const float*)d_in[7];
    const float* skipB   = (const float*)d_in[8];
    const float* resW    = (const float*)d_in[9];
    const float* resB    = (const float*)d_in[10];
    const float* last1W  = (const float*)d_in[11];
    const float* last1b  = (const float*)d_in[12];
    const float* last2W  = (const float*)d_in[13];
    const float* last2b  = (const float*)d_in[14];
    const float* convinW = (const float*)d_in[15];
    const float* upK     = (const float*)d_in[16];

    float* ws = (float*)d_ws;
    float* f0      = ws;                       // 10240
    float* f1      = f0 + 10240;               // 40960
    float* f2      = f1 + 40960;               // 163840
    float* f3      = f2 + 163840;              // 655360
    float* firstWT = f3 + 655360;              // 16384
    float* resA    = firstWT + 16384;          // 2097152
    float* resB_   = resA + 2097152;           // 2097152
    float* skipF   = resB_ + 2097152;          // 2097152
    unsigned short* mirA = (unsigned short*)(skipF + 2097152);  // 2097152
    unsigned short* mirB = mirA + 2097152;                      // 2097152
    unsigned short* ffb  = mirB + 2097152;                      // 3145728
    unsigned short* ATb  = ffb + 3145728;                       // 884736
    unsigned short* SRTb = ATb + 884736;                        // 196608
    unsigned short* W1b  = SRTb + 196608;                       // 4096
    unsigned short* W2b  = W1b + 4096;                          // 16384

    int n;
    n = NLAYERS * 128 * 288 + NLAYERS * 128 * 64 + 4096 + 16384 + 16384;
    k_pack<<<(n + 255) / 256, 256, 0, stream>>>(convW, condW, skipW, resW, last1W, last2W,
                                                firstW, firstb, ATb, SRTb, W1b, W2b, firstWT);
    n = NB * FCH * 64;
    k_convin<<<(n + 255) / 256, 256, 0, stream>>>(feature, convinW, f0);
    k_up<<<(NB * FCH * 256 + 255) / 256, 256, 0, stream>>>(f0, f1, upK + 0, 64);
    k_up<<<(NB * FCH * 1024 + 255) / 256, 256, 0, stream>>>(f1, f2, upK + 9, 256);
    k_up<<<(NB * FCH * 4096 + 255) / 256, 256, 0, stream>>>(f2, f3, upK + 18, 1024);
    k_up_last<<<NB * 256, 256, 0, stream>>>(f3, ffb, upK + 27);

    float* poF = resA;          float* pnF = resB_;
    unsigned short* poH = mirA; unsigned short* pnH = mirB;
    for (int s = 0; s < 4; ++s) {
        int flags = (s == 0 ? 1 : 0) | (s == 3 ? 2 : 0);
        k_stack<<<NB * 128, 512, 0, stream>>>(
            x, firstWT, poF, poH, pnF, pnH, skipF, ffb,
            ATb + (size_t)s * 6 * 128 * 288, SRTb + (size_t)s * 6 * 128 * 64,
            convB + s * 6 * 128, skipB + s * 6 * 64, resB + s * 6 * 64,
            W1b, last1b, W2b, last2b, (float*)d_out, flags);
        float* tf = poF; poF = pnF; pnF = tf;
        unsigned short* th = poH; poH = pnH; pnH = th;
    }
}